// Round 7
// baseline (300.863 us; speedup 1.0000x reference)
//
#include <hip/hip_runtime.h>
#include <hip/hip_bf16.h>
#include <stdint.h>

typedef unsigned short u16;
typedef __attribute__((ext_vector_type(4))) float f32x4;
typedef __attribute__((ext_vector_type(8))) short bf16x8;
typedef __attribute__((ext_vector_type(4))) unsigned short u16x4;
typedef __attribute__((ext_vector_type(8))) unsigned short u16x8;

__device__ inline u16 f2bf(float f) {
    unsigned int u = __builtin_bit_cast(unsigned int, f);
    u = u + 0x7fffu + ((u >> 16) & 1u);
    return (u16)(u >> 16);
}
__device__ inline float bf2f(u16 h) {
    return __builtin_bit_cast(float, ((unsigned int)h) << 16);
}
__device__ inline void gld_lds16(const void* g, void* l) {
    __builtin_amdgcn_global_load_lds((__attribute__((address_space(1))) void*)(g),
                                     (__attribute__((address_space(3))) void*)(l),
                                     16, 0, 0);
}

#define SB0() __builtin_amdgcn_sched_barrier(0)
#define BARRIER() do { __builtin_amdgcn_s_barrier(); SB0(); } while (0)
#define LGKM0()   do { asm volatile("s_waitcnt lgkmcnt(0)" ::: "memory"); SB0(); } while (0)

// ---------------------------------------------------------------------------
// 256x256 NT GEMM, BK=64, 512 thr = 8 waves (2M x 4N), 128x64 out per wave.
// DROPBAR=0: EXACT round-4 schedule (proven 85.6us/GEMM, no spill):
//   per phase: [stage][ds_reads][BARRIER][LGKM0][prio1 MFMA prio0][BARRIER]
// DROPBAR=1 (A/B on PV only): remove the pre-MFMA BARRIER, KEEP LGKM0
//   (LGKM0 pins read->use liveness; round-6 removed it and spilled).
//   per phase: [stage][ds_reads][LGKM0][prio1 MFMA prio0][BARRIER]
// Hazards (both variants): stageB(t+1) writes buf[1-cur] whose readers
// retired in tile t-1 (>=1 phase-end barrier earlier). stageA(t+2) (ph2/3)
// writes buf[cur] A: a0/a1 readers forced by LGKM0 before ph0/ph1 MFMA ->
// retired before ph1-end barrier; stage issues after it. vmcnt induction:
// tile start = 4 outstanding (A(t+1)); +8 staged = 12; vmcnt(4) retires
// A(t+1)+B(t+1) leaving A(t+2). Tail t>=NT-2: vmcnt(0).
// ---------------------------------------------------------------------------
template <int BF16OUT, int BIAS, int DROPBAR>
__global__ __launch_bounds__(512, 2)
void gemm256(const u16* __restrict__ A, const u16* __restrict__ B,
             void* __restrict__ Cv, const float* __restrict__ bias,
             int K, int lda, int ldb, int ldc,
             long sAb, long sBb, long sCb, float scale)
{
    __shared__ __align__(16) char lds[131072];

    const int tid  = threadIdx.x;
    const int lane = tid & 63;
    const int w    = tid >> 6;
    const int wm   = w >> 2, wn = w & 3;

    // XCD-aware bijective block swizzle (nwg % 8 == 0 for all our grids)
    const int gx   = gridDim.x, gy = gridDim.y;
    const int flat = blockIdx.x + gx * (blockIdx.y + gy * blockIdx.z);
    const int nwg  = gx * gy * gridDim.z;
    const int swz  = (flat & 7) * (nwg >> 3) + (flat >> 3);
    const int mt   = swz % gx;
    const int rest = swz / gx;
    const int ntl  = rest % gy;
    const int zb   = rest / gy;

    const u16* Ab = A + (long)zb * sAb;
    const u16* Bb = B + (long)zb * sBb;
    const long rowA0 = (long)mt * 256;
    const long rowB0 = (long)ntl * 256;

    // staging geometry: wave w covers rows w*16 + {0,8} + (lane>>3) of a half
    const int srow   = w * 16 + (lane >> 3);
    const int schunk = (lane & 7) ^ ((lane >> 3) & 7);
    const u16* aG = Ab + (rowA0 + srow) * (long)lda + schunk * 8;
    const u16* bG = Bb + (rowB0 + srow) * (long)ldb + schunk * 8;

    const int NT = K >> 6;

    auto stageA = [&](int t, int hh) {
        if (t >= NT) return;
        const u16* s = aG + (long)hh * 128 * lda + (long)t * 64;
        char* d = lds + (t & 1) * 65536 + hh * 16384 + w * 2048;
        gld_lds16(s, d);
        gld_lds16(s + 8 * (long)lda, d + 1024);
    };
    auto stageB = [&](int t, int hh) {
        if (t >= NT) return;
        const u16* s = bG + (long)hh * 128 * ldb + (long)t * 64;
        char* d = lds + (t & 1) * 65536 + 32768 + hh * 16384 + w * 2048;
        gld_lds16(s, d);
        gld_lds16(s + 8 * (long)ldb, d + 1024);
    };

    const int rl    = lane & 15;
    const int kbyte = (lane >> 4) * 16;
    auto ldA = [&](int cur, int m, int kh) -> bf16x8 {
        const int row = wm * 128 + m * 16 + rl;
        const int byt = (kh * 64 + kbyte) ^ ((row & 7) << 4);
        return *(const bf16x8*)(lds + cur * 65536 + row * 128 + byt);
    };
    auto ldB = [&](int cur, int n, int kh) -> bf16x8 {
        const int row = wn * 64 + n * 16 + rl;
        const int byt = (kh * 64 + kbyte) ^ ((row & 7) << 4);
        return *(const bf16x8*)(lds + cur * 65536 + 32768 + row * 128 + byt);
    };

    f32x4 acc[8][4] = {};
    bf16x8 a0[4][2], a1[4][2], b0[2][2], b1[2][2];

    // prologue: tile0 fully + tile1 A-halves; leave A(1) pair in flight
    stageA(0, 0); stageA(0, 1);
    stageB(0, 0); stageB(0, 1);
    stageA(1, 0); stageA(1, 1);
    asm volatile("s_waitcnt vmcnt(4)" ::: "memory");
    BARRIER();

    auto tile = [&](int t, const int cur) {
        // ---- phase 0: stage B0(t+1); read a0,b0; MFMA a0 x b0
        stageB(t + 1, 0);
#pragma unroll
        for (int m = 0; m < 4; ++m)
#pragma unroll
            for (int kh = 0; kh < 2; ++kh) a0[m][kh] = ldA(cur, m, kh);
#pragma unroll
        for (int n = 0; n < 2; ++n)
#pragma unroll
            for (int kh = 0; kh < 2; ++kh) b0[n][kh] = ldB(cur, n, kh);
        if (!DROPBAR) BARRIER();
        LGKM0();
        __builtin_amdgcn_s_setprio(1);
#pragma unroll
        for (int kh = 0; kh < 2; ++kh)
#pragma unroll
            for (int m = 0; m < 4; ++m)
#pragma unroll
                for (int n = 0; n < 2; ++n)
                    acc[m][n] = __builtin_amdgcn_mfma_f32_16x16x32_bf16(
                        a0[m][kh], b0[n][kh], acc[m][n], 0, 0, 0);
        __builtin_amdgcn_s_setprio(0);
        BARRIER();

        // ---- phase 1: stage B1(t+1); read a1; MFMA a1 x b0
        stageB(t + 1, 1);
#pragma unroll
        for (int m = 0; m < 4; ++m)
#pragma unroll
            for (int kh = 0; kh < 2; ++kh) a1[m][kh] = ldA(cur, m + 4, kh);
        if (!DROPBAR) BARRIER();
        LGKM0();
        __builtin_amdgcn_s_setprio(1);
#pragma unroll
        for (int kh = 0; kh < 2; ++kh)
#pragma unroll
            for (int m = 0; m < 4; ++m)
#pragma unroll
                for (int n = 0; n < 2; ++n)
                    acc[m + 4][n] = __builtin_amdgcn_mfma_f32_16x16x32_bf16(
                        a1[m][kh], b0[n][kh], acc[m + 4][n], 0, 0, 0);
        __builtin_amdgcn_s_setprio(0);
        BARRIER();

        // ---- phase 2: stage A0(t+2); read b1; MFMA a1 x b1
        stageA(t + 2, 0);
#pragma unroll
        for (int n = 0; n < 2; ++n)
#pragma unroll
            for (int kh = 0; kh < 2; ++kh) b1[n][kh] = ldB(cur, n + 2, kh);
        if (!DROPBAR) BARRIER();
        LGKM0();
        __builtin_amdgcn_s_setprio(1);
#pragma unroll
        for (int kh = 0; kh < 2; ++kh)
#pragma unroll
            for (int m = 0; m < 4; ++m)
#pragma unroll
                for (int n = 0; n < 2; ++n)
                    acc[m + 4][n + 2] = __builtin_amdgcn_mfma_f32_16x16x32_bf16(
                        a1[m][kh], b1[n][kh], acc[m + 4][n + 2], 0, 0, 0);
        __builtin_amdgcn_s_setprio(0);
        BARRIER();

        // ---- phase 3: stage A1(t+2); MFMA a0 x b1; boundary vmcnt
        stageA(t + 2, 1);
        if (!DROPBAR) BARRIER();
        __builtin_amdgcn_s_setprio(1);
#pragma unroll
        for (int kh = 0; kh < 2; ++kh)
#pragma unroll
            for (int m = 0; m < 4; ++m)
#pragma unroll
                for (int n = 0; n < 2; ++n)
                    acc[m][n + 2] = __builtin_amdgcn_mfma_f32_16x16x32_bf16(
                        a0[m][kh], b1[n][kh], acc[m][n + 2], 0, 0, 0);
        __builtin_amdgcn_s_setprio(0);
        if (t < NT - 2) { asm volatile("s_waitcnt vmcnt(4)" ::: "memory"); }
        else            { asm volatile("s_waitcnt vmcnt(0)" ::: "memory"); }
        BARRIER();
    };

    for (int t = 0; t < NT; t += 2) {  // NT is even (16 or 32)
        tile(t, 0);
        tile(t + 1, 1);
    }

    // epilogue: C/D layout col = lane&15, row = (lane>>4)*4 + j
#pragma unroll
    for (int m = 0; m < 8; ++m) {
#pragma unroll
        for (int n = 0; n < 4; ++n) {
            const long row0 = rowA0 + wm * 128 + m * 16 + (lane >> 4) * 4;
            const long col  = rowB0 + wn * 64 + n * 16 + (lane & 15);
            float bv = 0.0f;
            if (BIAS) bv = bias[col];
#pragma unroll
            for (int j = 0; j < 4; ++j) {
                const float val = acc[m][n][j] * scale + bv;
                const long  idx = (long)zb * sCb + (row0 + j) * ldc + col;
                if (BF16OUT) ((u16*)Cv)[idx] = f2bf(val);
                else         ((float*)Cv)[idx] = val;
            }
        }
    }
}

// ---------------------------------------------------------------------------
// In-place row softmax over 2048 bf16. One block (256 thr) per row.
// ---------------------------------------------------------------------------
__global__ __launch_bounds__(256)
void softmax_rows_bf16(u16* __restrict__ sc)
{
    __shared__ float redmax[4];
    __shared__ float redsum[4];
    const long row = blockIdx.x;
    u16x8* p = (u16x8*)(sc + row * 2048);
    const int t = threadIdx.x;

    u16x8 v = p[t];
    float f[8];
#pragma unroll
    for (int j = 0; j < 8; ++j) f[j] = bf2f(v[j]);

    float m = f[0];
#pragma unroll
    for (int j = 1; j < 8; ++j) m = fmaxf(m, f[j]);
#pragma unroll
    for (int o = 32; o; o >>= 1) m = fmaxf(m, __shfl_xor(m, o));
    if ((t & 63) == 0) redmax[t >> 6] = m;
    __syncthreads();
    m = fmaxf(fmaxf(redmax[0], redmax[1]), fmaxf(redmax[2], redmax[3]));

    float e[8], s = 0.0f;
#pragma unroll
    for (int j = 0; j < 8; ++j) { e[j] = __expf(f[j] - m); s += e[j]; }
#pragma unroll
    for (int o = 32; o; o >>= 1) s += __shfl_xor(s, o);
    if ((t & 63) == 0) redsum[t >> 6] = s;
    __syncthreads();
    s = redsum[0] + redsum[1] + redsum[2] + redsum[3];
    const float inv = 1.0f / s;

    u16x8 o;
#pragma unroll
    for (int j = 0; j < 8; ++j) o[j] = f2bf(e[j] * inv);
    p[t] = o;
}

// f32 -> bf16 elementwise, 4 elems/thread
__global__ __launch_bounds__(256)
void cvt_bf16(const float* __restrict__ src, u16* __restrict__ dst, long n4)
{
    const long i = (long)blockIdx.x * 256 + threadIdx.x;
    if (i >= n4) return;
    f32x4 v = ((const f32x4*)src)[i];
    u16x4 o;
#pragma unroll
    for (int j = 0; j < 4; ++j) o[j] = f2bf(v[j]);
    ((u16x4*)dst)[i] = o;
}

// x[b][n][d] f32 -> xb[b][n][d] bf16 (straight) + xT[b][d][n] bf16 (transposed)
__global__ __launch_bounds__(256)
void prep_x(const float* __restrict__ x, u16* __restrict__ xb, u16* __restrict__ xT)
{
    __shared__ float tile[32][33];
    const int  b  = blockIdx.z;
    const long n0 = (long)blockIdx.x * 32;
    const long d0 = (long)blockIdx.y * 32;
    const int  t  = threadIdx.x;
    const int  r  = t >> 3;
    const int  c  = (t & 7) * 4;

    f32x4 v = *(const f32x4*)(x + ((long)b * 2048 + n0 + r) * 1024 + d0 + c);
    u16x4 s;
#pragma unroll
    for (int j = 0; j < 4; ++j) { s[j] = f2bf(v[j]); tile[r][c + j] = v[j]; }
    *(u16x4*)(xb + ((long)b * 2048 + n0 + r) * 1024 + d0 + c) = s;
    __syncthreads();

    u16x4 o;
#pragma unroll
    for (int j = 0; j < 4; ++j) o[j] = f2bf(tile[c + j][r]);
    *(u16x4*)(xT + ((long)b * 1024 + d0 + r) * 2048 + n0 + c) = o;
}

// ---------------------------------------------------------------------------
// B=8, N=2048, DIM=1024.  ws layout (160 MB):
//   xT [8,1024,2048] bf16 @ 0      (32 MB)  live: prep -> PV
//   qk [16384,2048]  bf16 @ 32 MB  (64 MB)  live: proj -> scores
//   sc [8,2048,2048] bf16 @ 96 MB  (64 MB)  scores -> softmax -> PV
//   xb [8,2048,1024] bf16 @ 96 MB  (32 MB)  ALIAS under sc; dead before scores
//   Wb [2048,1024]   bf16 @ 128 MB ( 4 MB)  ALIAS under sc; dead before scores
// ---------------------------------------------------------------------------
extern "C" void kernel_launch(void* const* d_in, const int* in_sizes, int n_in,
                              void* d_out, int out_size, void* d_ws, size_t ws_size,
                              hipStream_t stream)
{
    const float* x   = (const float*)d_in[0];
    const float* Wqk = (const float*)d_in[1];
    const float* bqk = (const float*)d_in[2];
    float* out = (float*)d_out;

    char* ws = (char*)d_ws;
    u16* xT = (u16*)(ws);
    u16* qk = (u16*)(ws + 33554432L);
    u16* sc = (u16*)(ws + 100663296L);
    u16* xb = (u16*)(ws + 100663296L);
    u16* Wb = (u16*)(ws + 134217728L);

    cvt_bf16<<<2048, 256, 0, stream>>>(Wqk, Wb, 2048L * 1024 / 4);
    prep_x<<<dim3(64, 32, 8), 256, 0, stream>>>(x, xb, xT);

    // qk = x @ W^T + b  -> bf16 [16384, 2048]   (round-4 proven schedule)
    gemm256<1, 1, 0><<<dim3(64, 8, 1), 512, 0, stream>>>(
        xb, Wb, qk, bqk, 1024, 1024, 1024, 2048, 0, 0, 0, 1.0f);

    // sc[b] = k_b @ q_b^T / 32 -> bf16 [2048, 2048]   (round-4 proven schedule)
    gemm256<1, 0, 0><<<dim3(8, 8, 8), 512, 0, stream>>>(
        qk + 1024, qk, sc, nullptr, 1024, 2048, 2048, 2048,
        2048L * 2048, 2048L * 2048, 2048L * 2048, 0.03125f);

    // sc = softmax(sc) in place
    softmax_rows_bf16<<<16384, 256, 0, stream>>>(sc);

    // out[b] = attn_b @ x_b  (NT with xT) -> f32   (A/B: DROPBAR=1 variant)
    gemm256<0, 0, 1><<<dim3(8, 4, 8), 512, 0, stream>>>(
        sc, xT, out, nullptr, 2048, 2048, 2048, 1024,
        2048L * 2048, 1024L * 2048, 2048L * 1024, 1.0f);
}

// Round 9
// 262.025 us; speedup vs baseline: 1.1482x; 1.1482x over previous
//
#include <hip/hip_runtime.h>
#include <hip/hip_bf16.h>
#include <stdint.h>

typedef unsigned short u16;
typedef __attribute__((ext_vector_type(4))) float f32x4;
typedef __attribute__((ext_vector_type(8))) short bf16x8;
typedef __attribute__((ext_vector_type(4))) unsigned short u16x4;
typedef __attribute__((ext_vector_type(8))) unsigned short u16x8;

__device__ inline u16 f2bf(float f) {
    unsigned int u = __builtin_bit_cast(unsigned int, f);
    u = u + 0x7fffu + ((u >> 16) & 1u);
    return (u16)(u >> 16);
}
__device__ inline float bf2f(u16 h) {
    return __builtin_bit_cast(float, ((unsigned int)h) << 16);
}
__device__ inline void gld_lds16(const void* g, void* l) {
    __builtin_amdgcn_global_load_lds((__attribute__((address_space(1))) void*)(g),
                                     (__attribute__((address_space(3))) void*)(l),
                                     16, 0, 0);
}

#define SB0() __builtin_amdgcn_sched_barrier(0)
#define BARRIER() do { __builtin_amdgcn_s_barrier(); SB0(); } while (0)
#define LGKM0()   do { asm volatile("s_waitcnt lgkmcnt(0)" ::: "memory"); SB0(); } while (0)

// ---------------------------------------------------------------------------
// 256x256 NT GEMM, BK=64, 512 thr = 8 waves (2M x 4N), 128x64 out per wave.
// EXACT round-4 schedule (proven 85.6us/GEMM, VGPR 124, no spill):
// single runtime-cur t-loop, per phase:
//   [stage][ds_reads][BARRIER][LGKM0][prio1 MFMA prio0][BARRIER]
// Epilogue variants only (K-loop identical):
//   EXPOUT: write exp(val) (unnormalized softmax numerator)
//   RSCALE: scale by rs[zb*sRb + row] (softmax denominator reciprocal;
//           round-8 bug was missing the zb*sRb batch offset)
// ---------------------------------------------------------------------------
template <int BF16OUT, int BIAS, int EXPOUT, int RSCALE>
__global__ __launch_bounds__(512, 2)
void gemm256(const u16* __restrict__ A, const u16* __restrict__ B,
             void* __restrict__ Cv, const float* __restrict__ bias,
             const float* __restrict__ rs, long sRb,
             int K, int lda, int ldb, int ldc,
             long sAb, long sBb, long sCb, float scale)
{
    __shared__ __align__(16) char lds[131072];

    const int tid  = threadIdx.x;
    const int lane = tid & 63;
    const int w    = tid >> 6;
    const int wm   = w >> 2, wn = w & 3;

    // XCD-aware bijective block swizzle (nwg % 8 == 0 for all our grids)
    const int gx   = gridDim.x, gy = gridDim.y;
    const int flat = blockIdx.x + gx * (blockIdx.y + gy * blockIdx.z);
    const int nwg  = gx * gy * gridDim.z;
    const int swz  = (flat & 7) * (nwg >> 3) + (flat >> 3);
    const int mt   = swz % gx;
    const int rest = swz / gx;
    const int ntl  = rest % gy;
    const int zb   = rest / gy;

    const u16* Ab = A + (long)zb * sAb;
    const u16* Bb = B + (long)zb * sBb;
    const long rowA0 = (long)mt * 256;
    const long rowB0 = (long)ntl * 256;

    // staging geometry: wave w covers rows w*16 + {0,8} + (lane>>3) of a half
    const int srow   = w * 16 + (lane >> 3);
    const int schunk = (lane & 7) ^ ((lane >> 3) & 7);
    const u16* aG = Ab + (rowA0 + srow) * (long)lda + schunk * 8;
    const u16* bG = Bb + (rowB0 + srow) * (long)ldb + schunk * 8;

    const int NT = K >> 6;

    auto stageA = [&](int t, int hh) {
        if (t >= NT) return;
        const u16* s = aG + (long)hh * 128 * lda + (long)t * 64;
        char* d = lds + (t & 1) * 65536 + hh * 16384 + w * 2048;
        gld_lds16(s, d);
        gld_lds16(s + 8 * (long)lda, d + 1024);
    };
    auto stageB = [&](int t, int hh) {
        if (t >= NT) return;
        const u16* s = bG + (long)hh * 128 * ldb + (long)t * 64;
        char* d = lds + (t & 1) * 65536 + 32768 + hh * 16384 + w * 2048;
        gld_lds16(s, d);
        gld_lds16(s + 8 * (long)ldb, d + 1024);
    };

    const int rl    = lane & 15;
    const int kbyte = (lane >> 4) * 16;
    auto ldA = [&](int cur, int m, int kh) -> bf16x8 {
        const int row = wm * 128 + m * 16 + rl;
        const int byt = (kh * 64 + kbyte) ^ ((row & 7) << 4);
        return *(const bf16x8*)(lds + cur * 65536 + row * 128 + byt);
    };
    auto ldB = [&](int cur, int n, int kh) -> bf16x8 {
        const int row = wn * 64 + n * 16 + rl;
        const int byt = (kh * 64 + kbyte) ^ ((row & 7) << 4);
        return *(const bf16x8*)(lds + cur * 65536 + 32768 + row * 128 + byt);
    };

    f32x4 acc[8][4] = {};
    bf16x8 a0[4][2], a1[4][2], b0[2][2], b1[2][2];

    // prologue: tile0 fully + tile1 A-halves; leave A(1) pair in flight
    stageA(0, 0); stageA(0, 1);
    stageB(0, 0); stageB(0, 1);
    stageA(1, 0); stageA(1, 1);
    asm volatile("s_waitcnt vmcnt(4)" ::: "memory");
    BARRIER();

    for (int t = 0; t < NT; ++t) {
        const int cur = t & 1;

        // ---- phase 0: stage B0(t+1); read a0,b0; MFMA a0 x b0
        stageB(t + 1, 0);
#pragma unroll
        for (int m = 0; m < 4; ++m)
#pragma unroll
            for (int kh = 0; kh < 2; ++kh) a0[m][kh] = ldA(cur, m, kh);
#pragma unroll
        for (int n = 0; n < 2; ++n)
#pragma unroll
            for (int kh = 0; kh < 2; ++kh) b0[n][kh] = ldB(cur, n, kh);
        BARRIER();
        LGKM0();
        __builtin_amdgcn_s_setprio(1);
#pragma unroll
        for (int kh = 0; kh < 2; ++kh)
#pragma unroll
            for (int m = 0; m < 4; ++m)
#pragma unroll
                for (int n = 0; n < 2; ++n)
                    acc[m][n] = __builtin_amdgcn_mfma_f32_16x16x32_bf16(
                        a0[m][kh], b0[n][kh], acc[m][n], 0, 0, 0);
        __builtin_amdgcn_s_setprio(0);
        BARRIER();

        // ---- phase 1: stage B1(t+1); read a1; MFMA a1 x b0
        stageB(t + 1, 1);
#pragma unroll
        for (int m = 0; m < 4; ++m)
#pragma unroll
            for (int kh = 0; kh < 2; ++kh) a1[m][kh] = ldA(cur, m + 4, kh);
        BARRIER();
        LGKM0();
        __builtin_amdgcn_s_setprio(1);
#pragma unroll
        for (int kh = 0; kh < 2; ++kh)
#pragma unroll
            for (int m = 0; m < 4; ++m)
#pragma unroll
                for (int n = 0; n < 2; ++n)
                    acc[m + 4][n] = __builtin_amdgcn_mfma_f32_16x16x32_bf16(
                        a1[m][kh], b0[n][kh], acc[m + 4][n], 0, 0, 0);
        __builtin_amdgcn_s_setprio(0);
        BARRIER();

        // ---- phase 2: stage A0(t+2); read b1; MFMA a1 x b1
        stageA(t + 2, 0);
#pragma unroll
        for (int n = 0; n < 2; ++n)
#pragma unroll
            for (int kh = 0; kh < 2; ++kh) b1[n][kh] = ldB(cur, n + 2, kh);
        BARRIER();
        LGKM0();
        __builtin_amdgcn_s_setprio(1);
#pragma unroll
        for (int kh = 0; kh < 2; ++kh)
#pragma unroll
            for (int m = 0; m < 4; ++m)
#pragma unroll
                for (int n = 0; n < 2; ++n)
                    acc[m + 4][n + 2] = __builtin_amdgcn_mfma_f32_16x16x32_bf16(
                        a1[m][kh], b1[n][kh], acc[m + 4][n + 2], 0, 0, 0);
        __builtin_amdgcn_s_setprio(0);
        BARRIER();

        // ---- phase 3: stage A1(t+2); MFMA a0 x b1; boundary vmcnt
        stageA(t + 2, 1);
        BARRIER();
        __builtin_amdgcn_s_setprio(1);
#pragma unroll
        for (int kh = 0; kh < 2; ++kh)
#pragma unroll
            for (int m = 0; m < 4; ++m)
#pragma unroll
                for (int n = 0; n < 2; ++n)
                    acc[m][n + 2] = __builtin_amdgcn_mfma_f32_16x16x32_bf16(
                        a0[m][kh], b1[n][kh], acc[m][n + 2], 0, 0, 0);
        __builtin_amdgcn_s_setprio(0);
        if (t < NT - 2) { asm volatile("s_waitcnt vmcnt(4)" ::: "memory"); }
        else            { asm volatile("s_waitcnt vmcnt(0)" ::: "memory"); }
        SB0();
        BARRIER();
    }

    // epilogue: C/D layout col = lane&15, row = (lane>>4)*4 + j
#pragma unroll
    for (int m = 0; m < 8; ++m) {
        const long row0 = rowA0 + wm * 128 + m * 16 + (lane >> 4) * 4;
        float rv[4];
        if (RSCALE) {
#pragma unroll
            for (int j = 0; j < 4; ++j) rv[j] = rs[(long)zb * sRb + row0 + j];
        }
#pragma unroll
        for (int n = 0; n < 4; ++n) {
            const long col = rowB0 + wn * 64 + n * 16 + (lane & 15);
            float bv = 0.0f;
            if (BIAS) bv = bias[col];
#pragma unroll
            for (int j = 0; j < 4; ++j) {
                float val = acc[m][n][j] * scale + bv;
                if (EXPOUT) val = __expf(val);
                if (RSCALE) val *= rv[j];
                const long idx = (long)zb * sCb + (row0 + j) * ldc + col;
                if (BF16OUT) ((u16*)Cv)[idx] = f2bf(val);
                else         ((float*)Cv)[idx] = val;
            }
        }
    }
}

// ---------------------------------------------------------------------------
// rs[row] = 1 / sum_j sc[row][j]  (sc holds unnormalized exp, bf16, 2048 wide)
// One block (256 thr) per row; deterministic (no atomics).
// ---------------------------------------------------------------------------
__global__ __launch_bounds__(256)
void rowsum_inv(const u16* __restrict__ sc, float* __restrict__ rs)
{
    __shared__ float red[4];
    const long row = blockIdx.x;
    const u16x8* p = (const u16x8*)(sc + row * 2048);
    const int t = threadIdx.x;

    u16x8 v = p[t];
    float s = 0.0f;
#pragma unroll
    for (int j = 0; j < 8; ++j) s += bf2f(v[j]);
#pragma unroll
    for (int o = 32; o; o >>= 1) s += __shfl_xor(s, o);
    if ((t & 63) == 0) red[t >> 6] = s;
    __syncthreads();
    if (t == 0) rs[row] = 1.0f / (red[0] + red[1] + red[2] + red[3]);
}

// f32 -> bf16 elementwise, 4 elems/thread
__global__ __launch_bounds__(256)
void cvt_bf16(const float* __restrict__ src, u16* __restrict__ dst, long n4)
{
    const long i = (long)blockIdx.x * 256 + threadIdx.x;
    if (i >= n4) return;
    f32x4 v = ((const f32x4*)src)[i];
    u16x4 o;
#pragma unroll
    for (int j = 0; j < 4; ++j) o[j] = f2bf(v[j]);
    ((u16x4*)dst)[i] = o;
}

// x[b][n][d] f32 -> xb[b][n][d] bf16 (straight) + xT[b][d][n] bf16 (transposed)
__global__ __launch_bounds__(256)
void prep_x(const float* __restrict__ x, u16* __restrict__ xb, u16* __restrict__ xT)
{
    __shared__ float tile[32][33];
    const int  b  = blockIdx.z;
    const long n0 = (long)blockIdx.x * 32;
    const long d0 = (long)blockIdx.y * 32;
    const int  t  = threadIdx.x;
    const int  r  = t >> 3;
    const int  c  = (t & 7) * 4;

    f32x4 v = *(const f32x4*)(x + ((long)b * 2048 + n0 + r) * 1024 + d0 + c);
    u16x4 s;
#pragma unroll
    for (int j = 0; j < 4; ++j) { s[j] = f2bf(v[j]); tile[r][c + j] = v[j]; }
    *(u16x4*)(xb + ((long)b * 2048 + n0 + r) * 1024 + d0 + c) = s;
    __syncthreads();

    u16x4 o;
#pragma unroll
    for (int j = 0; j < 4; ++j) o[j] = f2bf(tile[c + j][r]);
    *(u16x4*)(xT + ((long)b * 1024 + d0 + r) * 2048 + n0 + c) = o;
}

// ---------------------------------------------------------------------------
// B=8, N=2048, DIM=1024.  ws layout (160 MB + 64 KB; 164 MB proven safe):
//   xT [8,1024,2048] bf16 @ 0      (32 MB)  live: prep -> PV
//   qk [16384,2048]  bf16 @ 32 MB  (64 MB)  live: proj -> scores
//   sc [8,2048,2048] bf16 @ 96 MB  (64 MB)  exp-scores -> rowsum -> PV
//   xb [8,2048,1024] bf16 @ 96 MB  (32 MB)  ALIAS under sc; dead before scores
//   Wb [2048,1024]   bf16 @ 128 MB ( 4 MB)  ALIAS under sc; dead before scores
//   rs [16384] f32        @ 160 MB (64 KB)  live: rowsum -> PV (no alias)
// ---------------------------------------------------------------------------
extern "C" void kernel_launch(void* const* d_in, const int* in_sizes, int n_in,
                              void* d_out, int out_size, void* d_ws, size_t ws_size,
                              hipStream_t stream)
{
    const float* x   = (const float*)d_in[0];
    const float* Wqk = (const float*)d_in[1];
    const float* bqk = (const float*)d_in[2];
    float* out = (float*)d_out;

    char* ws = (char*)d_ws;
    u16*   xT = (u16*)(ws);
    u16*   qk = (u16*)(ws + 33554432L);
    u16*   sc = (u16*)(ws + 100663296L);
    u16*   xb = (u16*)(ws + 100663296L);
    u16*   Wb = (u16*)(ws + 134217728L);
    float* rs = (float*)(ws + 167772160L);

    cvt_bf16<<<2048, 256, 0, stream>>>(Wqk, Wb, 2048L * 1024 / 4);
    prep_x<<<dim3(64, 32, 8), 256, 0, stream>>>(x, xb, xT);

    // qk = x @ W^T + b  -> bf16 [16384, 2048]
    gemm256<1, 1, 0, 0><<<dim3(64, 8, 1), 512, 0, stream>>>(
        xb, Wb, qk, bqk, nullptr, 0, 1024, 1024, 1024, 2048, 0, 0, 0, 1.0f);

    // sc[b] = exp(k_b @ q_b^T / 32)  (unnormalized softmax numerator, bf16)
    gemm256<1, 0, 1, 0><<<dim3(8, 8, 8), 512, 0, stream>>>(
        qk + 1024, qk, sc, nullptr, nullptr, 0, 1024, 2048, 2048, 2048,
        2048L * 2048, 2048L * 2048, 2048L * 2048, 0.03125f);

    // rs[i] = 1 / sum_j sc[i][j]
    rowsum_inv<<<16384, 256, 0, stream>>>(sc, rs);

    // out[b] = (sc_b @ x_b) * rs[zb*2048 + row]  (NT with xT) -> f32
    gemm256<0, 0, 0, 1><<<dim3(8, 4, 8), 512, 0, stream>>>(
        sc, xT, out, nullptr, rs, 2048, 2048, 2048, 2048, 1024,
        2048L * 2048, 1024L * 2048, 2048L * 1024, 1.0f);
}

// Round 10
// 257.931 us; speedup vs baseline: 1.1664x; 1.0159x over previous
//
#include <hip/hip_runtime.h>
#include <hip/hip_bf16.h>
#include <stdint.h>

typedef unsigned short u16;
typedef __attribute__((ext_vector_type(4))) float f32x4;
typedef __attribute__((ext_vector_type(8))) short bf16x8;
typedef __attribute__((ext_vector_type(4))) unsigned short u16x4;
typedef __attribute__((ext_vector_type(8))) unsigned short u16x8;

__device__ inline u16 f2bf(float f) {
    unsigned int u = __builtin_bit_cast(unsigned int, f);
    u = u + 0x7fffu + ((u >> 16) & 1u);
    return (u16)(u >> 16);
}
__device__ inline float bf2f(u16 h) {
    return __builtin_bit_cast(float, ((unsigned int)h) << 16);
}
__device__ inline void gld_lds16(const void* g, void* l) {
    __builtin_amdgcn_global_load_lds((__attribute__((address_space(1))) void*)(g),
                                     (__attribute__((address_space(3))) void*)(l),
                                     16, 0, 0);
}

#define SB0() __builtin_amdgcn_sched_barrier(0)
#define BARRIER() do { __builtin_amdgcn_s_barrier(); SB0(); } while (0)
#define LGKM0()   do { asm volatile("s_waitcnt lgkmcnt(0)" ::: "memory"); SB0(); } while (0)

// ---------------------------------------------------------------------------
// 256x256 NT GEMM, BK=64, 512 thr = 8 waves (2M x 4N), 128x64 out per wave.
// Round-9 proven base (85.6us/GEMM, VGPR 120, no spill): single runtime-cur
// t-loop, per phase [stage][ds_reads][BARRIER][LGKM0][prio1 MFMA prio0][BARRIER]
// DROPBAR=1 (A/B on PV only): remove the pre-MFMA BARRIER, KEEP LGKM0 (the
// liveness pin; round-6 removed it and spilled) and the runtime-cur loop
// (round-7's unroll-2 spilled). Hazards: every stage destination's readers
// were forced-retired by an LGKM0 >= 2 phase-end barriers earlier; per-wave
// issue order unchanged -> vmcnt(4) induction identical.
// Epilogue variants (K-loop identical):
//   EXPOUT: write exp(val)   PARTSUM: also write per-row partial sums
//   RSCALE: scale by rs[zb*sRb + row]
// ---------------------------------------------------------------------------
template <int BF16OUT, int BIAS, int EXPOUT, int RSCALE, int PARTSUM, int DROPBAR>
__global__ __launch_bounds__(512, 2)
void gemm256(const u16* __restrict__ A, const u16* __restrict__ B,
             void* __restrict__ Cv, const float* __restrict__ bias,
             const float* __restrict__ rs, long sRb, float* __restrict__ part,
             int K, int lda, int ldb, int ldc,
             long sAb, long sBb, long sCb, float scale)
{
    __shared__ __align__(16) char lds[131072];

    const int tid  = threadIdx.x;
    const int lane = tid & 63;
    const int w    = tid >> 6;
    const int wm   = w >> 2, wn = w & 3;

    // XCD-aware bijective block swizzle (nwg % 8 == 0 for all our grids)
    const int gx   = gridDim.x, gy = gridDim.y;
    const int flat = blockIdx.x + gx * (blockIdx.y + gy * blockIdx.z);
    const int nwg  = gx * gy * gridDim.z;
    const int swz  = (flat & 7) * (nwg >> 3) + (flat >> 3);
    const int mt   = swz % gx;
    const int rest = swz / gx;
    const int ntl  = rest % gy;
    const int zb   = rest / gy;

    const u16* Ab = A + (long)zb * sAb;
    const u16* Bb = B + (long)zb * sBb;
    const long rowA0 = (long)mt * 256;
    const long rowB0 = (long)ntl * 256;

    // staging geometry: wave w covers rows w*16 + {0,8} + (lane>>3) of a half
    const int srow   = w * 16 + (lane >> 3);
    const int schunk = (lane & 7) ^ ((lane >> 3) & 7);
    const u16* aG = Ab + (rowA0 + srow) * (long)lda + schunk * 8;
    const u16* bG = Bb + (rowB0 + srow) * (long)ldb + schunk * 8;

    const int NT = K >> 6;

    auto stageA = [&](int t, int hh) {
        if (t >= NT) return;
        const u16* s = aG + (long)hh * 128 * lda + (long)t * 64;
        char* d = lds + (t & 1) * 65536 + hh * 16384 + w * 2048;
        gld_lds16(s, d);
        gld_lds16(s + 8 * (long)lda, d + 1024);
    };
    auto stageB = [&](int t, int hh) {
        if (t >= NT) return;
        const u16* s = bG + (long)hh * 128 * ldb + (long)t * 64;
        char* d = lds + (t & 1) * 65536 + 32768 + hh * 16384 + w * 2048;
        gld_lds16(s, d);
        gld_lds16(s + 8 * (long)ldb, d + 1024);
    };

    const int rl    = lane & 15;
    const int kbyte = (lane >> 4) * 16;
    auto ldA = [&](int cur, int m, int kh) -> bf16x8 {
        const int row = wm * 128 + m * 16 + rl;
        const int byt = (kh * 64 + kbyte) ^ ((row & 7) << 4);
        return *(const bf16x8*)(lds + cur * 65536 + row * 128 + byt);
    };
    auto ldB = [&](int cur, int n, int kh) -> bf16x8 {
        const int row = wn * 64 + n * 16 + rl;
        const int byt = (kh * 64 + kbyte) ^ ((row & 7) << 4);
        return *(const bf16x8*)(lds + cur * 65536 + 32768 + row * 128 + byt);
    };

    f32x4 acc[8][4] = {};
    bf16x8 a0[4][2], a1[4][2], b0[2][2], b1[2][2];

    // prologue: tile0 fully + tile1 A-halves; leave A(1) pair in flight
    stageA(0, 0); stageA(0, 1);
    stageB(0, 0); stageB(0, 1);
    stageA(1, 0); stageA(1, 1);
    asm volatile("s_waitcnt vmcnt(4)" ::: "memory");
    BARRIER();

    for (int t = 0; t < NT; ++t) {
        const int cur = t & 1;

        // ---- phase 0: stage B0(t+1); read a0,b0; MFMA a0 x b0
        stageB(t + 1, 0);
#pragma unroll
        for (int m = 0; m < 4; ++m)
#pragma unroll
            for (int kh = 0; kh < 2; ++kh) a0[m][kh] = ldA(cur, m, kh);
#pragma unroll
        for (int n = 0; n < 2; ++n)
#pragma unroll
            for (int kh = 0; kh < 2; ++kh) b0[n][kh] = ldB(cur, n, kh);
        if (!DROPBAR) BARRIER();
        LGKM0();
        __builtin_amdgcn_s_setprio(1);
#pragma unroll
        for (int kh = 0; kh < 2; ++kh)
#pragma unroll
            for (int m = 0; m < 4; ++m)
#pragma unroll
                for (int n = 0; n < 2; ++n)
                    acc[m][n] = __builtin_amdgcn_mfma_f32_16x16x32_bf16(
                        a0[m][kh], b0[n][kh], acc[m][n], 0, 0, 0);
        __builtin_amdgcn_s_setprio(0);
        BARRIER();

        // ---- phase 1: stage B1(t+1); read a1; MFMA a1 x b0
        stageB(t + 1, 1);
#pragma unroll
        for (int m = 0; m < 4; ++m)
#pragma unroll
            for (int kh = 0; kh < 2; ++kh) a1[m][kh] = ldA(cur, m + 4, kh);
        if (!DROPBAR) BARRIER();
        LGKM0();
        __builtin_amdgcn_s_setprio(1);
#pragma unroll
        for (int kh = 0; kh < 2; ++kh)
#pragma unroll
            for (int m = 0; m < 4; ++m)
#pragma unroll
                for (int n = 0; n < 2; ++n)
                    acc[m + 4][n] = __builtin_amdgcn_mfma_f32_16x16x32_bf16(
                        a1[m][kh], b0[n][kh], acc[m + 4][n], 0, 0, 0);
        __builtin_amdgcn_s_setprio(0);
        BARRIER();

        // ---- phase 2: stage A0(t+2); read b1; MFMA a1 x b1
        stageA(t + 2, 0);
#pragma unroll
        for (int n = 0; n < 2; ++n)
#pragma unroll
            for (int kh = 0; kh < 2; ++kh) b1[n][kh] = ldB(cur, n + 2, kh);
        if (!DROPBAR) BARRIER();
        LGKM0();
        __builtin_amdgcn_s_setprio(1);
#pragma unroll
        for (int kh = 0; kh < 2; ++kh)
#pragma unroll
            for (int m = 0; m < 4; ++m)
#pragma unroll
                for (int n = 0; n < 2; ++n)
                    acc[m + 4][n + 2] = __builtin_amdgcn_mfma_f32_16x16x32_bf16(
                        a1[m][kh], b1[n][kh], acc[m + 4][n + 2], 0, 0, 0);
        __builtin_amdgcn_s_setprio(0);
        BARRIER();

        // ---- phase 3: stage A1(t+2); MFMA a0 x b1; boundary vmcnt
        stageA(t + 2, 1);
        if (!DROPBAR) BARRIER();
        __builtin_amdgcn_s_setprio(1);
#pragma unroll
        for (int kh = 0; kh < 2; ++kh)
#pragma unroll
            for (int m = 0; m < 4; ++m)
#pragma unroll
                for (int n = 0; n < 2; ++n)
                    acc[m][n + 2] = __builtin_amdgcn_mfma_f32_16x16x32_bf16(
                        a0[m][kh], b1[n][kh], acc[m][n + 2], 0, 0, 0);
        __builtin_amdgcn_s_setprio(0);
        if (t < NT - 2) { asm volatile("s_waitcnt vmcnt(4)" ::: "memory"); }
        else            { asm volatile("s_waitcnt vmcnt(0)" ::: "memory"); }
        SB0();
        BARRIER();
    }

    // epilogue: C/D layout col = lane&15, row = (lane>>4)*4 + j
#pragma unroll
    for (int m = 0; m < 8; ++m) {
        const long row0 = rowA0 + wm * 128 + m * 16 + (lane >> 4) * 4;
        float rv[4];
        if (RSCALE) {
#pragma unroll
            for (int j = 0; j < 4; ++j) rv[j] = rs[(long)zb * sRb + row0 + j];
        }
        float rsum[4] = {0.f, 0.f, 0.f, 0.f};
#pragma unroll
        for (int n = 0; n < 4; ++n) {
            const long col = rowB0 + wn * 64 + n * 16 + (lane & 15);
            float bv = 0.0f;
            if (BIAS) bv = bias[col];
#pragma unroll
            for (int j = 0; j < 4; ++j) {
                float val = acc[m][n][j] * scale + bv;
                if (EXPOUT) val = __expf(val);
                if (PARTSUM) rsum[j] += val;
                if (RSCALE) val *= rv[j];
                const long idx = (long)zb * sCb + (row0 + j) * ldc + col;
                if (BF16OUT) ((u16*)Cv)[idx] = f2bf(val);
                else         ((float*)Cv)[idx] = val;
            }
        }
        if (PARTSUM) {
            // reduce over the 16 col-lanes (same lane>>4 group)
#pragma unroll
            for (int j = 0; j < 4; ++j)
#pragma unroll
                for (int o = 1; o < 16; o <<= 1) rsum[j] += __shfl_xor(rsum[j], o);
            if ((lane & 15) == 0) {
#pragma unroll
                for (int j = 0; j < 4; ++j)
                    part[((long)zb * 2048 + row0 + j) * 32 + ntl * 4 + wn] = rsum[j];
            }
        }
    }
}

// ---------------------------------------------------------------------------
// rs[row] = 1 / sum_{q<32} part[row][q]   (part from scores epilogue, f32)
// 2 MB read instead of 64 MB sc re-read. Deterministic.
// ---------------------------------------------------------------------------
__global__ __launch_bounds__(256)
void rowsum_inv(const float* __restrict__ part, float* __restrict__ rs)
{
    const long row = (long)blockIdx.x * 256 + threadIdx.x;
    const f32x4* p = (const f32x4*)(part + row * 32);
    float s = 0.0f;
#pragma unroll
    for (int q = 0; q < 8; ++q) {
        f32x4 v = p[q];
        s += v[0] + v[1] + v[2] + v[3];
    }
    rs[row] = 1.0f / s;
}

// f32 -> bf16 elementwise, 4 elems/thread
__global__ __launch_bounds__(256)
void cvt_bf16(const float* __restrict__ src, u16* __restrict__ dst, long n4)
{
    const long i = (long)blockIdx.x * 256 + threadIdx.x;
    if (i >= n4) return;
    f32x4 v = ((const f32x4*)src)[i];
    u16x4 o;
#pragma unroll
    for (int j = 0; j < 4; ++j) o[j] = f2bf(v[j]);
    ((u16x4*)dst)[i] = o;
}

// x[b][n][d] f32 -> xb[b][n][d] bf16 (straight) + xT[b][d][n] bf16 (transposed)
__global__ __launch_bounds__(256)
void prep_x(const float* __restrict__ x, u16* __restrict__ xb, u16* __restrict__ xT)
{
    __shared__ float tile[32][33];
    const int  b  = blockIdx.z;
    const long n0 = (long)blockIdx.x * 32;
    const long d0 = (long)blockIdx.y * 32;
    const int  t  = threadIdx.x;
    const int  r  = t >> 3;
    const int  c  = (t & 7) * 4;

    f32x4 v = *(const f32x4*)(x + ((long)b * 2048 + n0 + r) * 1024 + d0 + c);
    u16x4 s;
#pragma unroll
    for (int j = 0; j < 4; ++j) { s[j] = f2bf(v[j]); tile[r][c + j] = v[j]; }
    *(u16x4*)(xb + ((long)b * 2048 + n0 + r) * 1024 + d0 + c) = s;
    __syncthreads();

    u16x4 o;
#pragma unroll
    for (int j = 0; j < 4; ++j) o[j] = f2bf(tile[c + j][r]);
    *(u16x4*)(xT + ((long)b * 1024 + d0 + r) * 2048 + n0 + c) = o;
}

// ---------------------------------------------------------------------------
// B=8, N=2048, DIM=1024.  ws layout (~162.1 MB; 164 MB proven safe):
//   xT [8,1024,2048] bf16 @ 0      (32 MB)  live: prep -> PV
//   qk [16384,2048]  bf16 @ 32 MB  (64 MB)  live: proj -> scores
//   sc [8,2048,2048] bf16 @ 96 MB  (64 MB)  exp-scores -> PV
//   xb [8,2048,1024] bf16 @ 96 MB  (32 MB)  ALIAS under sc; dead before scores
//   Wb [2048,1024]   bf16 @ 128 MB ( 4 MB)  ALIAS under sc; dead before scores
//   rs [16384] f32        @ 160 MB (64 KB)  rowsum -> PV
//   part [16384][32] f32  @ 160 MB+64KB (2 MB)  scores -> rowsum
// ---------------------------------------------------------------------------
extern "C" void kernel_launch(void* const* d_in, const int* in_sizes, int n_in,
                              void* d_out, int out_size, void* d_ws, size_t ws_size,
                              hipStream_t stream)
{
    const float* x   = (const float*)d_in[0];
    const float* Wqk = (const float*)d_in[1];
    const float* bqk = (const float*)d_in[2];
    float* out = (float*)d_out;

    char* ws = (char*)d_ws;
    u16*   xT   = (u16*)(ws);
    u16*   qk   = (u16*)(ws + 33554432L);
    u16*   sc   = (u16*)(ws + 100663296L);
    u16*   xb   = (u16*)(ws + 100663296L);
    u16*   Wb   = (u16*)(ws + 134217728L);
    float* rs   = (float*)(ws + 167772160L);
    float* part = (float*)(ws + 167837696L);

    cvt_bf16<<<2048, 256, 0, stream>>>(Wqk, Wb, 2048L * 1024 / 4);
    prep_x<<<dim3(64, 32, 8), 256, 0, stream>>>(x, xb, xT);

    // qk = x @ W^T + b  -> bf16 [16384, 2048]
    gemm256<1, 1, 0, 0, 0, 0><<<dim3(64, 8, 1), 512, 0, stream>>>(
        xb, Wb, qk, bqk, nullptr, 0, nullptr,
        1024, 1024, 1024, 2048, 0, 0, 0, 1.0f);

    // sc[b] = exp(k_b @ q_b^T / 32), plus per-row partial sums -> part
    gemm256<1, 0, 1, 0, 1, 0><<<dim3(8, 8, 8), 512, 0, stream>>>(
        qk + 1024, qk, sc, nullptr, nullptr, 0, part,
        1024, 2048, 2048, 2048,
        2048L * 2048, 2048L * 2048, 2048L * 2048, 0.03125f);

    // rs[i] = 1 / sum_q part[i][q]
    rowsum_inv<<<64, 256, 0, stream>>>(part, rs);

    // out[b] = (sc_b @ x_b) * rs[zb*2048 + row]  (DROPBAR=1 A/B variant)
    gemm256<0, 0, 0, 1, 0, 1><<<dim3(8, 4, 8), 512, 0, stream>>>(
        sc, xT, out, nullptr, rs, 2048, nullptr,
        2048, 2048, 2048, 1024,
        2048L * 2048, 1024L * 2048, 2048L * 1024, 1.0f);
}